// Round 14
// baseline (90.764 us; speedup 1.0000x reference)
//
#include <hip/hip_runtime.h>
#include <hip/hip_bf16.h>
#include <math.h>

#define BB   2
#define NN   8192
#define SS   1024
#define KK   32
#define HID  256
#define SENT 0xFFFFFFFFFFFFFFFFULL
#define LDB  264       // padded LDS row stride (bf16 elems)
#define WFE  65536     // frag elements per matrix copy (256*256)

typedef unsigned long long u64;
typedef unsigned int       u32;
typedef short bf16x8 __attribute__((ext_vector_type(8)));
typedef float f32x4  __attribute__((ext_vector_type(4)));

// sorted-4 insertion: compare-swap carry chain (keeps s0..s3 ascending, drops max)
#define CSW(SI) { const u64 mn = x < (SI) ? x : (SI); const u64 mx = x < (SI) ? (SI) : x; (SI) = mn; x = mx; }
#define INS(KV) { u64 x = (KV); CSW(s0) CSW(s1) CSW(s2) CSW(s3) }

// tanh via hardware exp/rcp: tanh(y) = 1 - 2/(1+e^{2y}); saturates correctly.
__device__ __forceinline__ float tanh_fast(float y) {
    const float e = __expf(2.0f * y);
    const float r = __builtin_amdgcn_rcpf(e + 1.0f);
    return fmaf(-2.0f, r, 1.0f);
}

__device__ __forceinline__ short bf_bits(float f) {
    const __hip_bfloat16 h = __float2bfloat16(f);   // RNE
    short s;
    __builtin_memcpy(&s, &h, 2);
    return s;
}

// popcount of mask restricted to lanes below me
__device__ __forceinline__ int mbcnt64(u64 m) {
    return (int)__builtin_amdgcn_mbcnt_hi((u32)(m >> 32),
           __builtin_amdgcn_mbcnt_lo((u32)m, 0u));
}

// ---- prep: split w1/w2 into bf16 hi+lo, MFMA B-frag order, ks-major grouping ----
// elem slot = mat*131072 + (((ks*16+ntg)*2+hl)*64+lane)*8 + j
// element  = W[k][n], k = ks*32 + (lane>>4)*8 + j, n = ntg*16 + (lane&15)
__global__ void prep_w(const float* __restrict__ w1, const float* __restrict__ w2,
                       __hip_bfloat16* __restrict__ wf) {
    const int idx = blockIdx.x * 256 + threadIdx.x;   // 0..131071
    const int j   = idx & 7;
    const int l   = (idx >> 3) & 63;
    const int ntg = (idx >> 9) & 15;
    const int ks  = (idx >> 13) & 7;
    const int mat = idx >> 16;
    const int k = ks * 32 + (l >> 4) * 8 + j;
    const int n = ntg * 16 + (l & 15);
    const float v = (mat ? w2 : w1)[k * HID + n];
    const __hip_bfloat16 hi = __float2bfloat16(v);
    const float res = v - __bfloat162float(hi);
    const size_t s0 = (size_t)mat * 131072 + ((size_t)((ks*16 + ntg)*2) * 64 + l) * 8 + j;
    wf[s0]       = hi;
    wf[s0 + 512] = __float2bfloat16(res);            // hl=1 slot
}

// ================= Kernel 1: KNN (pure selection, high occupancy) =================
// One block per token; proven R11 structure (PPT=32, ballot selection, fallback).
__global__ __launch_bounds__(256, 8)
void knn_kernel(const float* __restrict__ pos,     // (B,N,3)
                const int*   __restrict__ snidx,   // (S,)
                int*         __restrict__ nbr_g)   // (B*S, KK)
{
    const int bs   = blockIdx.x;        // 0 .. B*S-1
    const int b    = bs / SS;
    const int s    = bs - b * SS;
    const int t    = threadIdx.x;
    const int lane = t & 63;
    const int wv   = t >> 6;

    __shared__ u64 wl[4 * KK];          // 4 waves x 32 selected keys

    const float* posb = pos + (size_t)b * (NN * 3);
    const int   sp = snidx[s];
    const float sx = posb[sp*3 + 0];
    const float sy = posb[sp*3 + 1];
    const float sz = posb[sp*3 + 2];

    // ---- Phase 1: stream distances (reference rounding), per-lane sorted top-4 ----
    u64 s0=SENT,s1=SENT,s2=SENT,s3=SENT;
#pragma unroll 4
    for (int c = 0; c < 32; ++c) {
        const int i = c * 256 + t;                 // coalesced across lanes
        const float dx = __fsub_rn(sx, posb[i*3 + 0]);
        const float dy = __fsub_rn(sy, posb[i*3 + 1]);
        const float dz = __fsub_rn(sz, posb[i*3 + 2]);
        const float sq = __fadd_rn(__fadd_rn(__fmul_rn(dx,dx), __fmul_rn(dy,dy)),
                                   __fmul_rn(dz,dz));
        const u64 kv = ((u64)__float_as_uint(__fsqrt_rn(sq)) << 13) | (u32)i;
        INS(kv);
    }

    // ---- Phase 2: wave-level threshold selection (ballot binary search) ----
    {
        u64 L = 0;
        for (int bit = 43; bit >= 13; --bit) {
            const u64 cand = L | (1ull << bit);
            const int cnt = __popcll(__ballot(s0 < cand)) + __popcll(__ballot(s1 < cand))
                          + __popcll(__ballot(s2 < cand)) + __popcll(__ballot(s3 < cand));
            if (cnt < 32) L = cand;
        }
        u64 TH = L + (1ull << 13);
        {
            const int cnt = __popcll(__ballot(s0 < TH)) + __popcll(__ballot(s1 < TH))
                          + __popcll(__ballot(s2 < TH)) + __popcll(__ballot(s3 < TH));
            if (cnt != 32) {                       // distbit tie at cut: resolve by idx
                for (int bit = 12; bit >= 0; --bit) {
                    const u64 cand = L | (1ull << bit);
                    const int c2 = __popcll(__ballot(s0 < cand)) + __popcll(__ballot(s1 < cand))
                                 + __popcll(__ballot(s2 < cand)) + __popcll(__ballot(s3 < cand));
                    if (c2 < 32) L = cand;
                }
                TH = L + 1;
            }
        }
        const bool b0 = s0 < TH, b1 = s1 < TH, b2 = s2 < TH, b3 = s3 < TH;
        const int csel = (int)b0 + (int)b1 + (int)b2 + (int)b3;

        if (__ballot(csel == 4) != 0ull) {
            // Saturated lane (possible hidden 5th key < TH): proven serial fallback.
            int nv = 4;
#pragma unroll 1
            for (int it = 0; it < KK; ++it) {
                u64 m = s0;
#pragma unroll
                for (int off = 32; off > 0; off >>= 1) {
                    const u64 o = __shfl_xor(m, off, 64);
                    m = o < m ? o : m;
                }
                if (lane == 0) wl[wv*KK + it] = m;
                if (s0 == m) {
                    s0=s1; s1=s2; s2=s3; s3=SENT;
                    if (--nv == 0) {                // refill from stream, keys > m
                        const u64 last = m;
                        s0=s1=s2=s3=SENT;
#pragma unroll 4
                        for (int c = 0; c < 32; ++c) {
                            const int i = c * 256 + t;
                            const float dx = __fsub_rn(sx, posb[i*3 + 0]);
                            const float dy = __fsub_rn(sy, posb[i*3 + 1]);
                            const float dz = __fsub_rn(sz, posb[i*3 + 2]);
                            const float sq = __fadd_rn(__fadd_rn(__fmul_rn(dx,dx), __fmul_rn(dy,dy)),
                                                       __fmul_rn(dz,dz));
                            u64 kv = ((u64)__float_as_uint(__fsqrt_rn(sq)) << 13) | (u32)i;
                            kv = kv > last ? kv : SENT;
                            INS(kv);
                        }
                        nv = (int)(s0!=SENT)+(int)(s1!=SENT)+(int)(s2!=SENT)+(int)(s3!=SENT);
                    }
                }
            }
        } else {
            const u64 m0 = __ballot(b0), m1 = __ballot(b1),
                      m2 = __ballot(b2), m3 = __ballot(b3);
            const int pos2 = mbcnt64(m0) + mbcnt64(m1) + mbcnt64(m2) + mbcnt64(m3);
            u64* wwl = &wl[wv * KK];
            if (b0) wwl[pos2]     = s0;
            if (b1) wwl[pos2 + 1] = s1;
            if (b2) wwl[pos2 + 2] = s2;
            if (b3) wwl[pos2 + 3] = s3;
        }
    }
    __syncthreads();

    // ---- Phase 2b: block stage — top-32 of the 128 wave-selected keys ----
    if (t < 64) {
        const u64 k0 = wl[lane], k1 = wl[64 + lane];
        u64 L = 0;
        for (int bit = 43; bit >= 13; --bit) {
            const u64 cand = L | (1ull << bit);
            const int cnt = __popcll(__ballot(k0 < cand)) + __popcll(__ballot(k1 < cand));
            if (cnt < 32) L = cand;
        }
        u64 TH = L + (1ull << 13);
        {
            const int cnt = __popcll(__ballot(k0 < TH)) + __popcll(__ballot(k1 < TH));
            if (cnt != 32) {
                for (int bit = 12; bit >= 0; --bit) {
                    const u64 cand = L | (1ull << bit);
                    const int c2 = __popcll(__ballot(k0 < cand)) + __popcll(__ballot(k1 < cand));
                    if (c2 < 32) L = cand;
                }
                TH = L + 1;
            }
        }
        const bool c0 = k0 < TH, c1 = k1 < TH;
        const int p = mbcnt64(__ballot(c0)) + mbcnt64(__ballot(c1));
        if (c0) nbr_g[(size_t)bs * KK + p]           = (int)(k0 & 8191u);
        if (c1) nbr_g[(size_t)bs * KK + p + (int)c0] = (int)(k1 & 8191u);
    }
}

// ============ Kernel 2: embed + MLP (M=64 GEMM, 2 tokens per block) ============
__global__ __launch_bounds__(256, 4)
void mlp_kernel(const float* __restrict__ pos,     // (B,N,3)
                const int*   __restrict__ nbr_g,   // (B*S, KK)
                const float* __restrict__ w_in,    // (3,HID)
                const float* __restrict__ b_in,    // (HID,)
                const float* __restrict__ b1,      // (HID,)
                const float* __restrict__ b2,      // (HID,)
                const __hip_bfloat16* __restrict__ wf,
                float*       __restrict__ out)     // (B,S,HID)
{
    const int tk0  = blockIdx.x * 2;    // first token (b*SS + s), same b for both
    const int b    = tk0 / SS;
    const int t    = threadIdx.x;
    const int lane = t & 63;
    const int wv   = t >> 6;

    __shared__ __align__(16) short h0b[2 * KK][LDB]; // bf16 activations (33792 B)
    __shared__ __align__(16) float nbc[2 * 4 * KK];  // float4-strided coords

    const float* posb = pos + (size_t)b * (NN * 3);

    // ---- gather neighbor coords (float4-strided for b128 reads) ----
    if (t < 2 * KK * 3) {
        const int k = t / 3, d = t - 3 * k;        // k in [0,64): row (token*32+kk)
        nbc[k * 4 + d] = posb[(size_t)nbr_g[(size_t)tk0 * KK + k] * 3 + d];
    }
    __syncthreads();

    // ---- h0 = coords @ w_in + b_in + sincos PE -> bf16 (thread = channel) ----
    {
        const int  c     = t;
        const int  dimi  = c / 84;                  // 84 = 2*42 channels per dim
        const int  cc    = c - dimi * 84;
        const bool hasPe = c < 252;
        const bool isCos = cc >= 42;
        const int  f     = isCos ? cc - 42 : cc;
        const float fcoef = (float)(-9.210340371976184 / 41.0);
        const float freqv = expf((float)f * fcoef);
        const int  di    = hasPe ? dimi : 0;

        const float wi0 = w_in[0*HID + c];
        const float wi1 = w_in[1*HID + c];
        const float wi2 = w_in[2*HID + c];
        const float bi  = b_in[c];

#pragma unroll 4
        for (int k = 0; k < 2 * KK; ++k) {         // 64 rows (2 tokens x 32)
            const float4 xv4 = *(const float4*)&nbc[k * 4];   // one b128 read
            const float x0 = xv4.x, x1 = xv4.y, x2 = xv4.z;
            float v = fmaf(x2, wi2, fmaf(x1, wi1, fmaf(x0, wi0, bi)));
            if (hasPe) {
                const float xv  = (di == 0) ? x0 : ((di == 1) ? x1 : x2);
                const float ang = xv * freqv;
                v += isCos ? __cosf(ang) : __sinf(ang);   // native (args |x|<~6)
            }
            h0b[k][c] = bf_bits(v);
        }
    }
    __syncthreads();

    // ---- MLP via bf16 MFMA, split weights (hi+lo); M=64, wave owns 64 channels ----
    // A frag (16x16x32): row = lane&15, k = ks*32 + (lane>>4)*8 + j  (matches prep).
    // C/D: col = lane&15, row = (lane>>4)*4 + reg   [HW-verified m89]
    const int lr = lane & 15;
    const int lg = lane >> 4;
    const int nbase = wv * 64;

    const short* arow0 = &h0b[lr][lg * 8];
    const short* arow1 = &h0b[16 + lr][lg * 8];
    const short* arow2 = &h0b[32 + lr][lg * 8];
    const short* arow3 = &h0b[48 + lr][lg * 8];
    const __hip_bfloat16* wb1 = wf + (size_t)wv * 4096 + lane * 8;
    const __hip_bfloat16* wb2 = wb1 + 2 * WFE;

    f32x4 acc[4][4];

    // ---- layer 1: h1 = h0 @ w1 + b1 ----
    {
#pragma unroll
        for (int nt = 0; nt < 4; ++nt) {
            const float bias = b1[nbase + nt*16 + lr];
            const f32x4 bv = {bias, bias, bias, bias};
            acc[0][nt] = bv; acc[1][nt] = bv; acc[2][nt] = bv; acc[3][nt] = bv;
        }
#pragma unroll 1
        for (int ks = 0; ks < 8; ++ks) {
            const bf16x8 af0 = *(const bf16x8*)(arow0 + ks * 32);
            const bf16x8 af1 = *(const bf16x8*)(arow1 + ks * 32);
            const bf16x8 af2 = *(const bf16x8*)(arow2 + ks * 32);
            const bf16x8 af3 = *(const bf16x8*)(arow3 + ks * 32);
            const __hip_bfloat16* p = wb1 + ks * 16384;
#pragma unroll
            for (int nt = 0; nt < 4; ++nt) {
                const bf16x8 bh = *(const bf16x8*)(p + nt * 1024);
                acc[0][nt] = __builtin_amdgcn_mfma_f32_16x16x32_bf16(af0, bh, acc[0][nt], 0,0,0);
                acc[1][nt] = __builtin_amdgcn_mfma_f32_16x16x32_bf16(af1, bh, acc[1][nt], 0,0,0);
                acc[2][nt] = __builtin_amdgcn_mfma_f32_16x16x32_bf16(af2, bh, acc[2][nt], 0,0,0);
                acc[3][nt] = __builtin_amdgcn_mfma_f32_16x16x32_bf16(af3, bh, acc[3][nt], 0,0,0);
                const bf16x8 bl = *(const bf16x8*)(p + nt * 1024 + 512);
                acc[0][nt] = __builtin_amdgcn_mfma_f32_16x16x32_bf16(af0, bl, acc[0][nt], 0,0,0);
                acc[1][nt] = __builtin_amdgcn_mfma_f32_16x16x32_bf16(af1, bl, acc[1][nt], 0,0,0);
                acc[2][nt] = __builtin_amdgcn_mfma_f32_16x16x32_bf16(af2, bl, acc[2][nt], 0,0,0);
                acc[3][nt] = __builtin_amdgcn_mfma_f32_16x16x32_bf16(af3, bl, acc[3][nt], 0,0,0);
            }
        }
    }
    __syncthreads();                                 // all layer-1 h0 reads done

    // gelu (tanh approx) -> h0b (bf16; same rounding as before)
    {
        const float kA = 0.7978845608028654f;        // sqrt(2/pi)
#pragma unroll
        for (int mt = 0; mt < 4; ++mt)
#pragma unroll
        for (int nt = 0; nt < 4; ++nt)
#pragma unroll
        for (int r = 0; r < 4; ++r) {
            const float x  = acc[mt][nt][r];
            const float x3 = x * x * x;
            const float tv = tanh_fast(kA * fmaf(0.044715f, x3, x));
            h0b[mt*16 + lg*4 + r][nbase + nt*16 + lr] = bf_bits(0.5f * x * (1.0f + tv));
        }
    }
    __syncthreads();

    // ---- layer 2: g @ w2 (bias+mean folded into epilogue) ----
    {
        const f32x4 z = {0.f, 0.f, 0.f, 0.f};
#pragma unroll
        for (int nt = 0; nt < 4; ++nt) {
            acc[0][nt] = z; acc[1][nt] = z; acc[2][nt] = z; acc[3][nt] = z;
        }
#pragma unroll 1
        for (int ks = 0; ks < 8; ++ks) {
            const bf16x8 af0 = *(const bf16x8*)(arow0 + ks * 32);
            const bf16x8 af1 = *(const bf16x8*)(arow1 + ks * 32);
            const bf16x8 af2 = *(const bf16x8*)(arow2 + ks * 32);
            const bf16x8 af3 = *(const bf16x8*)(arow3 + ks * 32);
            const __hip_bfloat16* p = wb2 + ks * 16384;
#pragma unroll
            for (int nt = 0; nt < 4; ++nt) {
                const bf16x8 bh = *(const bf16x8*)(p + nt * 1024);
                acc[0][nt] = __builtin_amdgcn_mfma_f32_16x16x32_bf16(af0, bh, acc[0][nt], 0,0,0);
                acc[1][nt] = __builtin_amdgcn_mfma_f32_16x16x32_bf16(af1, bh, acc[1][nt], 0,0,0);
                acc[2][nt] = __builtin_amdgcn_mfma_f32_16x16x32_bf16(af2, bh, acc[2][nt], 0,0,0);
                acc[3][nt] = __builtin_amdgcn_mfma_f32_16x16x32_bf16(af3, bh, acc[3][nt], 0,0,0);
                const bf16x8 bl = *(const bf16x8*)(p + nt * 1024 + 512);
                acc[0][nt] = __builtin_amdgcn_mfma_f32_16x16x32_bf16(af0, bl, acc[0][nt], 0,0,0);
                acc[1][nt] = __builtin_amdgcn_mfma_f32_16x16x32_bf16(af1, bl, acc[1][nt], 0,0,0);
                acc[2][nt] = __builtin_amdgcn_mfma_f32_16x16x32_bf16(af2, bl, acc[2][nt], 0,0,0);
                acc[3][nt] = __builtin_amdgcn_mfma_f32_16x16x32_bf16(af3, bl, acc[3][nt], 0,0,0);
            }
        }
    }

    // ---- epilogue: per-token mean over 32 rows + b2; lanes<16 write ----
#pragma unroll
    for (int nt = 0; nt < 4; ++nt) {
        float sumA = 0.0f, sumB = 0.0f;
#pragma unroll
        for (int r = 0; r < 4; ++r) {
            sumA += acc[0][nt][r] + acc[1][nt][r];   // rows 0-31  (token 0)
            sumB += acc[2][nt][r] + acc[3][nt][r];   // rows 32-63 (token 1)
        }
        sumA += __shfl_xor(sumA, 16, 64); sumA += __shfl_xor(sumA, 32, 64);
        sumB += __shfl_xor(sumB, 16, 64); sumB += __shfl_xor(sumB, 32, 64);
        if (lane < 16) {
            const int ch = wv * 64 + nt*16 + lane;
            const float bb = b2[ch];
            out[(size_t)tk0 * HID + ch]       = fmaf(sumA, 1.0f / KK, bb);
            out[(size_t)(tk0 + 1) * HID + ch] = fmaf(sumB, 1.0f / KK, bb);
        }
    }
}

extern "C" void kernel_launch(void* const* d_in, const int* in_sizes, int n_in,
                              void* d_out, int out_size, void* d_ws, size_t ws_size,
                              hipStream_t stream) {
    const float* pos  = (const float*)d_in[0];
    const int*   sni  = (const int*)  d_in[1];
    const float* w_in = (const float*)d_in[2];
    const float* b_in = (const float*)d_in[3];
    const float* w1   = (const float*)d_in[4];
    const float* b1   = (const float*)d_in[5];
    const float* w2   = (const float*)d_in[6];
    const float* b2   = (const float*)d_in[7];
    float* out = (float*)d_out;
    __hip_bfloat16* wf = (__hip_bfloat16*)d_ws;            // 512 KB
    int* nbr_g = (int*)((char*)d_ws + 4 * WFE * 2);        // +256 KB (B*S*KK ints)
    (void)ws_size; (void)in_sizes; (void)n_in; (void)out_size;

    hipLaunchKernelGGL(prep_w, dim3(2 * WFE / 256), dim3(256), 0, stream, w1, w2, wf);
    hipLaunchKernelGGL(knn_kernel, dim3(BB * SS), dim3(256), 0, stream, pos, sni, nbr_g);
    hipLaunchKernelGGL(mlp_kernel, dim3(BB * SS / 2), dim3(256), 0, stream,
                       pos, nbr_g, w_in, b_in, b1, b2, wf, out);
}

// Round 15
// 78.452 us; speedup vs baseline: 1.1569x; 1.1569x over previous
//
#include <hip/hip_runtime.h>
#include <hip/hip_bf16.h>
#include <math.h>

#define BB   2
#define NN   8192
#define SS   1024
#define KK   32
#define HID  256
#define SENT 0xFFFFFFFFFFFFFFFFULL
#define LDB  264       // padded LDS row stride (bf16 elems)
#define WFE  65536     // frag elements per matrix copy (256*256)

typedef unsigned long long u64;
typedef unsigned int       u32;
typedef short bf16x8 __attribute__((ext_vector_type(8)));
typedef float f32x4  __attribute__((ext_vector_type(4)));

// compare-swap carry chain step
#define CSW(SI) { const u64 mn = x < (SI) ? x : (SI); const u64 mx = x < (SI) ? (SI) : x; (SI) = mn; x = mx; }
#define INS5(KV) { u64 x = (KV); CSW(s0) CSW(s1) CSW(s2) CSW(s3) CSW(s4) }
#define INS3HI(KV) { u64 x = (KV); CSW(s5) CSW(s6) CSW(s7) }
#define INS8(KV) { u64 x = (KV); CSW(s0) CSW(s1) CSW(s2) CSW(s3) CSW(s4) CSW(s5) CSW(s6) CSW(s7) }

#define DIST_KEY(i, kv)                                                        \
    const float dx = __fsub_rn(sx, posb[(i)*3 + 0]);                           \
    const float dy = __fsub_rn(sy, posb[(i)*3 + 1]);                           \
    const float dz = __fsub_rn(sz, posb[(i)*3 + 2]);                           \
    const float sq = __fadd_rn(__fadd_rn(__fmul_rn(dx,dx), __fmul_rn(dy,dy)),  \
                               __fmul_rn(dz,dz));                              \
    const u64 kv = ((u64)__float_as_uint(__fsqrt_rn(sq)) << 13) | (u32)(i);

// tanh via hardware exp/rcp: tanh(y) = 1 - 2/(1+e^{2y}); saturates correctly.
__device__ __forceinline__ float tanh_fast(float y) {
    const float e = __expf(2.0f * y);
    const float r = __builtin_amdgcn_rcpf(e + 1.0f);
    return fmaf(-2.0f, r, 1.0f);
}

__device__ __forceinline__ short bf_bits(float f) {
    const __hip_bfloat16 h = __float2bfloat16(f);   // RNE
    short s;
    __builtin_memcpy(&s, &h, 2);
    return s;
}

__device__ __forceinline__ int mbcnt64(u64 m) {
    return (int)__builtin_amdgcn_mbcnt_hi((u32)(m >> 32),
           __builtin_amdgcn_mbcnt_lo((u32)m, 0u));
}

// ---- prep: split w1/w2 into bf16 hi+lo, MFMA B-frag order, ks-major grouping ----
__global__ void prep_w(const float* __restrict__ w1, const float* __restrict__ w2,
                       __hip_bfloat16* __restrict__ wf) {
    const int idx = blockIdx.x * 256 + threadIdx.x;   // 0..131071
    const int j   = idx & 7;
    const int l   = (idx >> 3) & 63;
    const int ntg = (idx >> 9) & 15;
    const int ks  = (idx >> 13) & 7;
    const int mat = idx >> 16;
    const int k = ks * 32 + (l >> 4) * 8 + j;
    const int n = ntg * 16 + (l & 15);
    const float v = (mat ? w2 : w1)[k * HID + n];
    const __hip_bfloat16 hi = __float2bfloat16(v);
    const float res = v - __bfloat162float(hi);
    const size_t s0 = (size_t)mat * 131072 + ((size_t)((ks*16 + ntg)*2) * 64 + l) * 8 + j;
    wf[s0]       = hi;
    wf[s0 + 512] = __float2bfloat16(res);            // hl=1 slot
}

// ================= Kernel 1: KNN (ballot selection, 3-tier exactness) ============
__global__ __launch_bounds__(256, 8)
void knn_kernel(const float* __restrict__ pos,     // (B,N,3)
                const int*   __restrict__ snidx,   // (S,)
                int*         __restrict__ nbr_g)   // (B*S, KK)
{
    const int bs   = blockIdx.x;        // 0 .. B*S-1
    const int b    = bs / SS;
    const int s    = bs - b * SS;
    const int t    = threadIdx.x;
    const int lane = t & 63;
    const int wv   = t >> 6;

    __shared__ u64 wl[4 * KK];          // 4 waves x 32 selected keys

    const float* posb = pos + (size_t)b * (NN * 3);
    const int   sp = snidx[s];
    const float sx = posb[sp*3 + 0];
    const float sy = posb[sp*3 + 1];
    const float sz = posb[sp*3 + 2];

    // ---- Phase 1: stream distances, per-lane sorted top-5 (depth-5) ----
    u64 s0=SENT,s1=SENT,s2=SENT,s3=SENT,s4=SENT,s5=SENT,s6=SENT,s7=SENT;
#pragma unroll 4
    for (int c = 0; c < 32; ++c) {
        const int i = c * 256 + t;
        DIST_KEY(i, kv)
        INS5(kv);
    }

#define CNT5(CAND) (__popcll(__ballot(s0<(CAND)))+__popcll(__ballot(s1<(CAND))) \
                   +__popcll(__ballot(s2<(CAND)))+__popcll(__ballot(s3<(CAND))) \
                   +__popcll(__ballot(s4<(CAND))))
#define CNT8(CAND) (CNT5(CAND)+__popcll(__ballot(s5<(CAND))) \
                   +__popcll(__ballot(s6<(CAND)))+__popcll(__ballot(s7<(CAND))))

    // ---- Phase 2: wave threshold selection (ballot binary search, depth-5) ----
    {
        u64 L = 0;
        for (int bit = 43; bit >= 13; --bit) {
            const u64 cand = L | (1ull << bit);
            if (CNT5(cand) < 32) L = cand;
        }
        u64 TH = L + (1ull << 13);
        if (CNT5(TH) != 32) {                      // distbit tie: resolve by idx
            for (int bit = 12; bit >= 0; --bit) {
                const u64 cand = L | (1ull << bit);
                if (CNT5(cand) < 32) L = cand;
            }
            TH = L + 1;
        }
        bool b0 = s0 < TH, b1 = s1 < TH, b2 = s2 < TH, b3 = s3 < TH, b4 = s4 < TH;
        bool b5 = false, b6 = false, b7 = false;
        const int csel5 = (int)b0+(int)b1+(int)b2+(int)b3+(int)b4;
        bool need_serial = false;

        if (__ballot(csel5 == 5) != 0ull) {
            // Tier 2 (P~1%/wave): extend all lanes to verified depth-8, redo search.
            s5 = s6 = s7 = SENT;
#pragma unroll 4
            for (int c = 0; c < 32; ++c) {
                const int i = c * 256 + t;
                DIST_KEY(i, kv)
                const u64 kf = kv > s4 ? kv : SENT;   // keys beyond the depth-5 max
                INS3HI(kf);
            }
            u64 L8 = 0;
            for (int bit = 43; bit >= 13; --bit) {
                const u64 cand = L8 | (1ull << bit);
                if (CNT8(cand) < 32) L8 = cand;
            }
            u64 TH8 = L8 + (1ull << 13);
            if (CNT8(TH8) != 32) {
                for (int bit = 12; bit >= 0; --bit) {
                    const u64 cand = L8 | (1ull << bit);
                    if (CNT8(cand) < 32) L8 = cand;
                }
                TH8 = L8 + 1;
            }
            b0 = s0 < TH8; b1 = s1 < TH8; b2 = s2 < TH8; b3 = s3 < TH8;
            b4 = s4 < TH8; b5 = s5 < TH8; b6 = s6 < TH8; b7 = s7 < TH8;
            const int csel8 = (int)b0+(int)b1+(int)b2+(int)b3
                            + (int)b4+(int)b5+(int)b6+(int)b7;
            need_serial = __ballot(csel8 == 8) != 0ull;
        }

        if (need_serial) {
            // Tier 3 (P~1e-3/launch): proven R8 serial extraction, depth-8 buffer.
            int nv = (int)(s0!=SENT)+(int)(s1!=SENT)+(int)(s2!=SENT)+(int)(s3!=SENT)
                   + (int)(s4!=SENT)+(int)(s5!=SENT)+(int)(s6!=SENT)+(int)(s7!=SENT);
#pragma unroll 1
            for (int it = 0; it < KK; ++it) {
                u64 m = s0;
#pragma unroll
                for (int off = 32; off > 0; off >>= 1) {
                    const u64 o = __shfl_xor(m, off, 64);
                    m = o < m ? o : m;
                }
                if (lane == 0) wl[wv*KK + it] = m;
                if (s0 == m) {
                    s0=s1; s1=s2; s2=s3; s3=s4; s4=s5; s5=s6; s6=s7; s7=SENT;
                    if (--nv == 0) {                // refill from stream, keys > m
                        const u64 last = m;
                        s0=s1=s2=s3=s4=s5=s6=s7=SENT;
#pragma unroll 4
                        for (int c = 0; c < 32; ++c) {
                            const int i = c * 256 + t;
                            DIST_KEY(i, kv)
                            const u64 kf = kv > last ? kv : SENT;
                            INS8(kf);
                        }
                        nv = (int)(s0!=SENT)+(int)(s1!=SENT)+(int)(s2!=SENT)+(int)(s3!=SENT)
                           + (int)(s4!=SENT)+(int)(s5!=SENT)+(int)(s6!=SENT)+(int)(s7!=SENT);
                    }
                }
            }
        } else {
            // Compaction (covers depth-5 and depth-8 fast paths; order irrelevant).
            const u64 m0=__ballot(b0), m1=__ballot(b1), m2=__ballot(b2), m3=__ballot(b3),
                      m4=__ballot(b4), m5=__ballot(b5), m6=__ballot(b6), m7=__ballot(b7);
            int p = mbcnt64(m0)+mbcnt64(m1)+mbcnt64(m2)+mbcnt64(m3)
                  + mbcnt64(m4)+mbcnt64(m5)+mbcnt64(m6)+mbcnt64(m7);
            u64* wwl = &wl[wv * KK];
            // sorted buffer => selection flags are a prefix; offsets are sequential
            if (b0) { wwl[p] = s0; ++p; }
            if (b1) { wwl[p] = s1; ++p; }
            if (b2) { wwl[p] = s2; ++p; }
            if (b3) { wwl[p] = s3; ++p; }
            if (b4) { wwl[p] = s4; ++p; }
            if (b5) { wwl[p] = s5; ++p; }
            if (b6) { wwl[p] = s6; ++p; }
            if (b7) { wwl[p] = s7; }
        }
    }
    __syncthreads();

    // ---- Phase 2b: block stage — top-32 of the 128 wave-selected keys ----
    if (t < 64) {
        const u64 k0 = wl[lane], k1 = wl[64 + lane];
        u64 L = 0;
        for (int bit = 43; bit >= 13; --bit) {
            const u64 cand = L | (1ull << bit);
            const int cnt = __popcll(__ballot(k0 < cand)) + __popcll(__ballot(k1 < cand));
            if (cnt < 32) L = cand;
        }
        u64 TH = L + (1ull << 13);
        {
            const int cnt = __popcll(__ballot(k0 < TH)) + __popcll(__ballot(k1 < TH));
            if (cnt != 32) {
                for (int bit = 12; bit >= 0; --bit) {
                    const u64 cand = L | (1ull << bit);
                    const int c2 = __popcll(__ballot(k0 < cand)) + __popcll(__ballot(k1 < cand));
                    if (c2 < 32) L = cand;
                }
                TH = L + 1;
            }
        }
        const bool c0 = k0 < TH, c1 = k1 < TH;
        const int p = mbcnt64(__ballot(c0)) + mbcnt64(__ballot(c1));
        if (c0) nbr_g[(size_t)bs * KK + p]           = (int)(k0 & 8191u);
        if (c1) nbr_g[(size_t)bs * KK + p + (int)c0] = (int)(k1 & 8191u);
    }
}

// ============ Kernel 2: embed + MLP (M=64 GEMM, 2 tokens per block) ============
__global__ __launch_bounds__(256, 4)
void mlp_kernel(const float* __restrict__ pos,     // (B,N,3)
                const int*   __restrict__ nbr_g,   // (B*S, KK)
                const float* __restrict__ w_in,    // (3,HID)
                const float* __restrict__ b_in,    // (HID,)
                const float* __restrict__ b1,      // (HID,)
                const float* __restrict__ b2,      // (HID,)
                const __hip_bfloat16* __restrict__ wf,
                float*       __restrict__ out)     // (B,S,HID)
{
    const int tk0  = blockIdx.x * 2;    // first token (b*SS + s), same b for both
    const int b    = tk0 / SS;
    const int t    = threadIdx.x;
    const int lane = t & 63;
    const int wv   = t >> 6;

    __shared__ __align__(16) short h0b[2 * KK][LDB]; // bf16 activations (33792 B)
    __shared__ __align__(16) float nbc[2 * 4 * KK];  // float4-strided coords

    const float* posb = pos + (size_t)b * (NN * 3);

    // ---- gather neighbor coords (float4-strided for b128 reads) ----
    if (t < 2 * KK * 3) {
        const int k = t / 3, d = t - 3 * k;        // k in [0,64): row (token*32+kk)
        nbc[k * 4 + d] = posb[(size_t)nbr_g[(size_t)tk0 * KK + k] * 3 + d];
    }
    __syncthreads();

    // ---- h0 = coords @ w_in + b_in + sincos PE -> bf16 (thread = channel) ----
    {
        const int  c     = t;
        const int  dimi  = c / 84;                  // 84 = 2*42 channels per dim
        const int  cc    = c - dimi * 84;
        const bool hasPe = c < 252;
        const bool isCos = cc >= 42;
        const int  f     = isCos ? cc - 42 : cc;
        const float fcoef = (float)(-9.210340371976184 / 41.0);
        const float freqv = expf((float)f * fcoef);
        const int  di    = hasPe ? dimi : 0;

        const float wi0 = w_in[0*HID + c];
        const float wi1 = w_in[1*HID + c];
        const float wi2 = w_in[2*HID + c];
        const float bi  = b_in[c];

#pragma unroll 4
        for (int k = 0; k < 2 * KK; ++k) {         // 64 rows (2 tokens x 32)
            const float4 xv4 = *(const float4*)&nbc[k * 4];   // one b128 read
            const float x0 = xv4.x, x1 = xv4.y, x2 = xv4.z;
            float v = fmaf(x2, wi2, fmaf(x1, wi1, fmaf(x0, wi0, bi)));
            if (hasPe) {
                const float xv  = (di == 0) ? x0 : ((di == 1) ? x1 : x2);
                const float ang = xv * freqv;
                v += isCos ? __cosf(ang) : __sinf(ang);   // native (args |x|<~6)
            }
            h0b[k][c] = bf_bits(v);
        }
    }
    __syncthreads();

    // ---- MLP via bf16 MFMA, split weights (hi+lo); M=64, wave owns 64 channels ----
    // A frag (16x16x32): row = lane&15, k = ks*32 + (lane>>4)*8 + j  (matches prep).
    // C/D: col = lane&15, row = (lane>>4)*4 + reg   [HW-verified m89]
    const int lr = lane & 15;
    const int lg = lane >> 4;
    const int nbase = wv * 64;

    const short* arow0 = &h0b[lr][lg * 8];
    const short* arow1 = &h0b[16 + lr][lg * 8];
    const short* arow2 = &h0b[32 + lr][lg * 8];
    const short* arow3 = &h0b[48 + lr][lg * 8];
    const __hip_bfloat16* wb1 = wf + (size_t)wv * 4096 + lane * 8;
    const __hip_bfloat16* wb2 = wb1 + 2 * WFE;

    f32x4 acc[4][4];

    // ---- layer 1: h1 = h0 @ w1 + b1 ----
    {
#pragma unroll
        for (int nt = 0; nt < 4; ++nt) {
            const float bias = b1[nbase + nt*16 + lr];
            const f32x4 bv = {bias, bias, bias, bias};
            acc[0][nt] = bv; acc[1][nt] = bv; acc[2][nt] = bv; acc[3][nt] = bv;
        }
#pragma unroll 1
        for (int ks = 0; ks < 8; ++ks) {
            const bf16x8 af0 = *(const bf16x8*)(arow0 + ks * 32);
            const bf16x8 af1 = *(const bf16x8*)(arow1 + ks * 32);
            const bf16x8 af2 = *(const bf16x8*)(arow2 + ks * 32);
            const bf16x8 af3 = *(const bf16x8*)(arow3 + ks * 32);
            const __hip_bfloat16* p = wb1 + ks * 16384;
#pragma unroll
            for (int nt = 0; nt < 4; ++nt) {
                const bf16x8 bh = *(const bf16x8*)(p + nt * 1024);
                acc[0][nt] = __builtin_amdgcn_mfma_f32_16x16x32_bf16(af0, bh, acc[0][nt], 0,0,0);
                acc[1][nt] = __builtin_amdgcn_mfma_f32_16x16x32_bf16(af1, bh, acc[1][nt], 0,0,0);
                acc[2][nt] = __builtin_amdgcn_mfma_f32_16x16x32_bf16(af2, bh, acc[2][nt], 0,0,0);
                acc[3][nt] = __builtin_amdgcn_mfma_f32_16x16x32_bf16(af3, bh, acc[3][nt], 0,0,0);
                const bf16x8 bl = *(const bf16x8*)(p + nt * 1024 + 512);
                acc[0][nt] = __builtin_amdgcn_mfma_f32_16x16x32_bf16(af0, bl, acc[0][nt], 0,0,0);
                acc[1][nt] = __builtin_amdgcn_mfma_f32_16x16x32_bf16(af1, bl, acc[1][nt], 0,0,0);
                acc[2][nt] = __builtin_amdgcn_mfma_f32_16x16x32_bf16(af2, bl, acc[2][nt], 0,0,0);
                acc[3][nt] = __builtin_amdgcn_mfma_f32_16x16x32_bf16(af3, bl, acc[3][nt], 0,0,0);
            }
        }
    }
    __syncthreads();                                 // all layer-1 h0 reads done

    // gelu (tanh approx) -> h0b (bf16; same rounding as before)
    {
        const float kA = 0.7978845608028654f;        // sqrt(2/pi)
#pragma unroll
        for (int mt = 0; mt < 4; ++mt)
#pragma unroll
        for (int nt = 0; nt < 4; ++nt)
#pragma unroll
        for (int r = 0; r < 4; ++r) {
            const float x  = acc[mt][nt][r];
            const float x3 = x * x * x;
            const float tv = tanh_fast(kA * fmaf(0.044715f, x3, x));
            h0b[mt*16 + lg*4 + r][nbase + nt*16 + lr] = bf_bits(0.5f * x * (1.0f + tv));
        }
    }
    __syncthreads();

    // ---- layer 2: g @ w2 (bias+mean folded into epilogue) ----
    {
        const f32x4 z = {0.f, 0.f, 0.f, 0.f};
#pragma unroll
        for (int nt = 0; nt < 4; ++nt) {
            acc[0][nt] = z; acc[1][nt] = z; acc[2][nt] = z; acc[3][nt] = z;
        }
#pragma unroll 1
        for (int ks = 0; ks < 8; ++ks) {
            const bf16x8 af0 = *(const bf16x8*)(arow0 + ks * 32);
            const bf16x8 af1 = *(const bf16x8*)(arow1 + ks * 32);
            const bf16x8 af2 = *(const bf16x8*)(arow2 + ks * 32);
            const bf16x8 af3 = *(const bf16x8*)(arow3 + ks * 32);
            const __hip_bfloat16* p = wb2 + ks * 16384;
#pragma unroll
            for (int nt = 0; nt < 4; ++nt) {
                const bf16x8 bh = *(const bf16x8*)(p + nt * 1024);
                acc[0][nt] = __builtin_amdgcn_mfma_f32_16x16x32_bf16(af0, bh, acc[0][nt], 0,0,0);
                acc[1][nt] = __builtin_amdgcn_mfma_f32_16x16x32_bf16(af1, bh, acc[1][nt], 0,0,0);
                acc[2][nt] = __builtin_amdgcn_mfma_f32_16x16x32_bf16(af2, bh, acc[2][nt], 0,0,0);
                acc[3][nt] = __builtin_amdgcn_mfma_f32_16x16x32_bf16(af3, bh, acc[3][nt], 0,0,0);
                const bf16x8 bl = *(const bf16x8*)(p + nt * 1024 + 512);
                acc[0][nt] = __builtin_amdgcn_mfma_f32_16x16x32_bf16(af0, bl, acc[0][nt], 0,0,0);
                acc[1][nt] = __builtin_amdgcn_mfma_f32_16x16x32_bf16(af1, bl, acc[1][nt], 0,0,0);
                acc[2][nt] = __builtin_amdgcn_mfma_f32_16x16x32_bf16(af2, bl, acc[2][nt], 0,0,0);
                acc[3][nt] = __builtin_amdgcn_mfma_f32_16x16x32_bf16(af3, bl, acc[3][nt], 0,0,0);
            }
        }
    }

    // ---- epilogue: per-token mean over 32 rows + b2; lanes<16 write ----
#pragma unroll
    for (int nt = 0; nt < 4; ++nt) {
        float sumA = 0.0f, sumB = 0.0f;
#pragma unroll
        for (int r = 0; r < 4; ++r) {
            sumA += acc[0][nt][r] + acc[1][nt][r];   // rows 0-31  (token 0)
            sumB += acc[2][nt][r] + acc[3][nt][r];   // rows 32-63 (token 1)
        }
        sumA += __shfl_xor(sumA, 16, 64); sumA += __shfl_xor(sumA, 32, 64);
        sumB += __shfl_xor(sumB, 16, 64); sumB += __shfl_xor(sumB, 32, 64);
        if (lane < 16) {
            const int ch = wv * 64 + nt*16 + lane;
            const float bb = b2[ch];
            out[(size_t)tk0 * HID + ch]       = fmaf(sumA, 1.0f / KK, bb);
            out[(size_t)(tk0 + 1) * HID + ch] = fmaf(sumB, 1.0f / KK, bb);
        }
    }
}

extern "C" void kernel_launch(void* const* d_in, const int* in_sizes, int n_in,
                              void* d_out, int out_size, void* d_ws, size_t ws_size,
                              hipStream_t stream) {
    const float* pos  = (const float*)d_in[0];
    const int*   sni  = (const int*)  d_in[1];
    const float* w_in = (const float*)d_in[2];
    const float* b_in = (const float*)d_in[3];
    const float* w1   = (const float*)d_in[4];
    const float* b1   = (const float*)d_in[5];
    const float* w2   = (const float*)d_in[6];
    const float* b2   = (const float*)d_in[7];
    float* out = (float*)d_out;
    __hip_bfloat16* wf = (__hip_bfloat16*)d_ws;            // 512 KB
    int* nbr_g = (int*)((char*)d_ws + 4 * WFE * 2);        // +256 KB (B*S*KK ints)
    (void)ws_size; (void)in_sizes; (void)n_in; (void)out_size;

    hipLaunchKernelGGL(prep_w, dim3(2 * WFE / 256), dim3(256), 0, stream, w1, w2, wf);
    hipLaunchKernelGGL(knn_kernel, dim3(BB * SS), dim3(256), 0, stream, pos, sni, nbr_g);
    hipLaunchKernelGGL(mlp_kernel, dim3(BB * SS / 2), dim3(256), 0, stream,
                       pos, nbr_g, w_in, b_in, b1, b2, wf, out);
}